// Round 14
// baseline (1649.192 us; speedup 1.0000x reference)
//
#include <hip/hip_runtime.h>

#define NREL 8
#define SCHUNK 2048

typedef __attribute__((ext_vector_type(8))) short bf16x8;
typedef __attribute__((ext_vector_type(4))) float f32x4;

__device__ __forceinline__ float bf2f(ushort u) {
  union { unsigned u; float f; } c; c.u = ((unsigned)u) << 16; return c.f;
}
__device__ __forceinline__ ushort f2bf(float f) {
  union { float f; unsigned u; } c; c.f = f;
  unsigned r = c.u + 0x7FFFu + ((c.u >> 16) & 1u);   // round-to-nearest-even
  return (ushort)(r >> 16);
}

// ======================= CSR build =======================
__global__ void hist_k(const int* __restrict__ dst, const int* __restrict__ et,
                       int* __restrict__ cnt, int nE) {
  int i = blockIdx.x * blockDim.x + threadIdx.x;
  if (i < nE) atomicAdd(&cnt[dst[i] * NREL + et[i]], 1);
}

__global__ void scan1_k(const int* __restrict__ cnt, int n,
                        int* __restrict__ thexc, int* __restrict__ bsum) {
  __shared__ int sh[256];
  int b = blockIdx.x, t = threadIdx.x;
  int base = b * SCHUNK + t * 8;
  int s = 0;
#pragma unroll
  for (int j = 0; j < 8; ++j) { int idx = base + j; s += (idx < n) ? cnt[idx] : 0; }
  sh[t] = s;
  __syncthreads();
  for (int d = 1; d < 256; d <<= 1) {
    int v = (t >= d) ? sh[t - d] : 0;
    __syncthreads();
    sh[t] += v;
    __syncthreads();
  }
  thexc[b * 256 + t] = sh[t] - s;
  if (t == 255) bsum[b] = sh[255];
}

__global__ void scan2_k(int* __restrict__ bsum, int nb, int total,
                        int* __restrict__ off, int n) {
  int run = 0;
  for (int i = 0; i < nb; ++i) { int v = bsum[i]; bsum[i] = run; run += v; }
  off[n] = total;
}

__global__ void scan3_k(const int* __restrict__ cnt, int n, const int* __restrict__ thexc,
                        const int* __restrict__ bsum, int* __restrict__ off,
                        int* __restrict__ cur) {
  int b = blockIdx.x, t = threadIdx.x;
  int base = b * SCHUNK + t * 8;
  int run = bsum[b] + thexc[b * 256 + t];
#pragma unroll
  for (int j = 0; j < 8; ++j) {
    int idx = base + j;
    if (idx < n) { int c = cnt[idx]; off[idx] = run; cur[idx] = run; run += c; }
  }
}

__global__ void fill2_k(const int* __restrict__ src, const int* __restrict__ dst,
                        const int* __restrict__ et, int nE,
                        int* __restrict__ cur, int* __restrict__ slist) {
  int i = blockIdx.x * blockDim.x + threadIdx.x;
  if (i < nE) {
    int seg = dst[i] * NREL + et[i];
    int p = atomicAdd(&cur[seg], 1);
    slist[p] = src[i];
  }
}

// ======================= conversions =======================
__global__ void f2b_k(const float* __restrict__ in, ushort* __restrict__ out, int n4) {
  int i = blockIdx.x * blockDim.x + threadIdx.x;
  if (i < n4) {
    float4 v = *(const float4*)(in + (size_t)i * 4);
    ushort4 o;
    o.x = f2bf(v.x); o.y = f2bf(v.y); o.z = f2bf(v.z); o.w = f2bf(v.w);
    *(ushort4*)(out + (size_t)i * 4) = o;
  }
}

// W[r][d][o] fp32 -> Wt[(r/G)][o][(r%G)*K + d] bf16
__global__ void wt_k(const float* __restrict__ W, ushort* __restrict__ Wt,
                     int R, int K, int O, int G) {
  size_t i = (size_t)blockIdx.x * blockDim.x + threadIdx.x;
  size_t tot = (size_t)R * K * O;
  if (i >= tot) return;
  int o = (int)(i % O);
  size_t t = i / O;
  int d = (int)(t % K);
  int r = (int)(t / K);
  Wt[((size_t)(r / G) * O + o) * ((size_t)G * K) + (size_t)(r % G) * K + d] = f2bf(W[i]);
}

// ===== gather NR relations per dst row, ILP-4 over the contiguous edge range =====
template<int D, int NR>
__global__ void gatherN_k(const ushort* __restrict__ xb, const int* __restrict__ slist,
                          const int* __restrict__ off, int r0,
                          ushort* __restrict__ agg, int N) {
  constexpr int V = D / 64;  // ushorts per lane
  const int lane = threadIdx.x & 63;
  const int d = (blockIdx.x * blockDim.x + threadIdx.x) >> 6;
  if (d >= N) return;
  int o[NR + 1];
#pragma unroll
  for (int j = 0; j <= NR; ++j) o[j] = off[d * NREL + r0 + j];
  const int bc = lane * V;
  float s[NR][V];
#pragma unroll
  for (int r = 0; r < NR; ++r)
#pragma unroll
    for (int v = 0; v < V; ++v) s[r][v] = 0.f;

  const int base = o[0], total = o[NR] - base;
  for (int i0 = 0; i0 < total; i0 += 4) {
    uint  raw2[4];
    uint2 raw4[4];
#pragma unroll
    for (int u = 0; u < 4; ++u) {
      if (i0 + u < total) {
        int e = slist[base + i0 + u];
        const ushort* xp = xb + (size_t)e * D + bc;
        if constexpr (V == 2) raw2[u] = *(const uint*)xp;
        else                  raw4[u] = *(const uint2*)xp;
      }
    }
#pragma unroll
    for (int u = 0; u < 4; ++u) {
      if (i0 + u < total) {
        int gj = base + i0 + u;
        float f[V];
        if constexpr (V == 2) {
          f[0] = bf2f((ushort)(raw2[u] & 0xffff));
          f[1] = bf2f((ushort)(raw2[u] >> 16));
        } else {
          f[0] = bf2f((ushort)(raw4[u].x & 0xffff));
          f[1] = bf2f((ushort)(raw4[u].x >> 16));
          f[2] = bf2f((ushort)(raw4[u].y & 0xffff));
          f[3] = bf2f((ushort)(raw4[u].y >> 16));
        }
#pragma unroll
        for (int r = 0; r < NR; ++r) {
          if (gj >= o[r] && gj < o[r + 1]) {
#pragma unroll
            for (int v = 0; v < V; ++v) s[r][v] += f[v];
          }
        }
      }
    }
  }

#pragma unroll
  for (int r = 0; r < NR; ++r) {
    int c = o[r + 1] - o[r];
    float w = 1.f / (float)(c > 1 ? c : 1);
    ushort* mp = agg + (size_t)d * (NR * D) + r * D + bc;
    if constexpr (V == 2) {
      ushort2 st; st.x = f2bf(s[r][0] * w); st.y = f2bf(s[r][1] * w);
      *(ushort2*)mp = st;
    } else {
      ushort4 st; st.x = f2bf(s[r][0] * w); st.y = f2bf(s[r][1] * w);
      st.z = f2bf(s[r][2] * w); st.w = f2bf(s[r][3] * w);
      *(ushort4*)mp = st;
    }
  }
}

// ============ bf16 MFMA GEMM, PF=2 reg-staged pipeline, dual A-source ============
// C (+)= A1[M,K1]@B1t^T [+ A2[M,K2]@B2t^T] [+bias][relu].  B*t are [O][K] row-major.
// 128x128 tile, 4 waves (2x2), wave = 64x64 via 4x4 frags of 16x16x32. BK=64, XOR-swizzled LDS.
template<bool CF32>
__global__ __launch_bounds__(256)
void mgemm_k(const ushort* __restrict__ A1, int K1, const ushort* __restrict__ B1t,
             const ushort* __restrict__ A2, int K2, const ushort* __restrict__ B2t,
             const float* __restrict__ bias, void* __restrict__ Cv,
             int loadC, int relu, int M, int O) {
  __shared__ ushort Al[128 * 64];
  __shared__ ushort Bl[128 * 64];
  const int tid = threadIdx.x;
  const int lane = tid & 63;
  const int w = tid >> 6;
  const int wr = (w >> 1) * 64;
  const int wc = (w & 1) * 64;
  const int m0 = blockIdx.x * 128;
  const int n0 = blockIdx.y * 128;

  f32x4 acc[4][4];
#pragma unroll
  for (int i = 0; i < 4; ++i)
#pragma unroll
    for (int j = 0; j < 4; ++j) acc[i][j] = (f32x4){0.f, 0.f, 0.f, 0.f};

  const int srow = tid >> 3;   // 0..31
  const int schk = tid & 7;    // 0..7 (16B chunk within 128B row)

  const int nt1 = K1 >> 6;
  const int nt2 = A2 ? (K2 >> 6) : 0;
  const int nt = nt1 + nt2;

  uint4 ra[2][4], rb[2][4];    // two staged k-tiles in flight
  auto gload = [&](int t, int s) {
    const ushort* PA; const ushort* PB; int Kk, k0;
    if (t < nt1) { PA = A1; PB = B1t; Kk = K1; k0 = t << 6; }
    else         { PA = A2; PB = B2t; Kk = K2; k0 = (t - nt1) << 6; }
#pragma unroll
    for (int p = 0; p < 4; ++p) {
      int row = p * 32 + srow;
      int gm = m0 + row;
      ra[s][p] = make_uint4(0, 0, 0, 0);
      if (gm < M) ra[s][p] = *(const uint4*)(PA + (size_t)gm * Kk + k0 + schk * 8);
      rb[s][p] = *(const uint4*)(PB + (size_t)(n0 + row) * Kk + k0 + schk * 8);
    }
  };
  auto swrite = [&](int s) {
#pragma unroll
    for (int p = 0; p < 4; ++p) {
      int row = p * 32 + srow;
      *(uint4*)&Al[row * 64 + ((schk ^ (row & 7)) * 8)] = ra[s][p];
      *(uint4*)&Bl[row * 64 + ((schk ^ (row & 7)) * 8)] = rb[s][p];
    }
  };

  gload(0, 0);
  if (nt > 1) gload(1, 1);
  for (int t = 0; t < nt; ++t) {
    swrite(t & 1);               // counted-vmcnt wait: only this tile's 8 loads
    __syncthreads();
    if (t + 2 < nt) gload(t + 2, t & 1);   // in flight across 2 compute phases
#pragma unroll
    for (int kk = 0; kk < 2; ++kk) {
      bf16x8 a_f[4], b_f[4];
      int slot = kk * 4 + (lane >> 4);
#pragma unroll
      for (int f = 0; f < 4; ++f) {
        int mr = wr + f * 16 + (lane & 15);
        a_f[f] = *(const bf16x8*)&Al[mr * 64 + ((slot ^ (mr & 7)) * 8)];
        int nc = wc + f * 16 + (lane & 15);
        b_f[f] = *(const bf16x8*)&Bl[nc * 64 + ((slot ^ (nc & 7)) * 8)];
      }
#pragma unroll
      for (int i = 0; i < 4; ++i)
#pragma unroll
        for (int j = 0; j < 4; ++j)
          acc[i][j] = __builtin_amdgcn_mfma_f32_16x16x32_bf16(a_f[i], b_f[j], acc[i][j], 0, 0, 0);
    }
    __syncthreads();
  }

  float bv[4];
#pragma unroll
  for (int j = 0; j < 4; ++j) bv[j] = bias ? bias[n0 + wc + j * 16 + (lane & 15)] : 0.f;
#pragma unroll
  for (int i = 0; i < 4; ++i) {
#pragma unroll
    for (int rg = 0; rg < 4; ++rg) {
      int row = m0 + wr + i * 16 + (lane >> 4) * 4 + rg;
      if (row < M) {
#pragma unroll
        for (int j = 0; j < 4; ++j) {
          int col = n0 + wc + j * 16 + (lane & 15);
          float v = acc[i][j][rg] + bv[j];
          if (CF32) {
            float* C = (float*)Cv + (size_t)row * O + col;
            if (loadC) v += *C;
            if (relu) v = fmaxf(v, 0.f);
            *C = v;
          } else {
            ushort* C = (ushort*)Cv + (size_t)row * O + col;
            if (loadC) v += bf2f(*C);
            if (relu) v = fmaxf(v, 0.f);
            *C = f2bf(v);
          }
        }
      }
    }
  }
}

extern "C" void kernel_launch(void* const* d_in, const int* in_sizes, int n_in,
                              void* d_out, int out_size, void* d_ws, size_t ws_size,
                              hipStream_t stream) {
  const float* x  = (const float*)d_in[0];
  const int* eidx = (const int*)d_in[1];
  const int* etyp = (const int*)d_in[2];
  const float* W1 = (const float*)d_in[3];
  const float* r1 = (const float*)d_in[4];
  const float* b1 = (const float*)d_in[5];
  const float* W2 = (const float*)d_in[6];
  const float* r2 = (const float*)d_in[7];
  const float* b2 = (const float*)d_in[8];
  const float* W3 = (const float*)d_in[9];
  const float* r3 = (const float*)d_in[10];
  const float* b3 = (const float*)d_in[11];
  float* out = (float*)d_out;

  const int N = in_sizes[0] / 128;  // 50000
  const int E = in_sizes[2];        // 800000
  const int* src = eidx;
  const int* dst = eidx + E;
  const int NSEG = N * NREL;
  const int NB = (NSEG + SCHUNK - 1) / SCHUNK;
  (void)n_in; (void)out_size;

  // workspace carve (== round-13 footprint, proven to fit)
  auto al = [](size_t v) { return (v + 255) & ~(size_t)255; };
  char* p = (char*)d_ws;
  int* cnt    = (int*)p;    p += al((size_t)NSEG * 4);
  int* off    = (int*)p;    p += al((size_t)(NSEG + 1) * 4);
  int* thexc  = (int*)p;    p += al((size_t)NB * 256 * 4);
  int* bsum   = (int*)p;    p += al((size_t)NB * 4);
  int* slist  = (int*)p;    p += al((size_t)E * 4);
  ushort* xb  = (ushort*)p; p += al((size_t)N * 128 * 2);
  ushort* h1  = (ushort*)p; p += al((size_t)N * 256 * 2);
  ushort* h2  = (ushort*)p; p += al((size_t)N * 256 * 2);
  ushort* agg = (ushort*)p; p += al((size_t)N * 1024 * 2);   // [N][NR*D] = [N][1024]
  ushort* wt1 = (ushort*)p; p += al((size_t)NREL * 128 * 256 * 2);
  ushort* rt1 = (ushort*)p; p += al((size_t)128 * 256 * 2);
  ushort* wt2 = (ushort*)p; p += al((size_t)NREL * 256 * 256 * 2);
  ushort* rt2 = (ushort*)p; p += al((size_t)256 * 256 * 2);
  ushort* wt3 = (ushort*)p; p += al((size_t)NREL * 256 * 128 * 2);
  ushort* rt3 = (ushort*)p; p += al((size_t)256 * 128 * 2);
  size_t used = (size_t)(p - (char*)d_ws);
  if (used > ws_size) return;  // fail clean, not SIGABRT

  // Insurance (proven necessary in R12): identical initial ws state every call.
  hipMemsetAsync(d_ws, 0, used, stream);

  // ---- CSR over (dst,rel), built once per call ----
  hist_k<<<(E + 255) / 256, 256, 0, stream>>>(dst, etyp, cnt, E);
  scan1_k<<<NB, 256, 0, stream>>>(cnt, NSEG, thexc, bsum);
  scan2_k<<<1, 1, 0, stream>>>(bsum, NB, E, off, NSEG);
  scan3_k<<<NB, 256, 0, stream>>>(cnt, NSEG, thexc, bsum, off, cnt);
  fill2_k<<<(E + 255) / 256, 256, 0, stream>>>(src, dst, etyp, E, cnt, slist);

  // ---- conversions ----
  f2b_k<<<(N * 128 / 4 + 255) / 256, 256, 0, stream>>>(x, xb, N * 128 / 4);
  auto wconv = [&](const float* W, ushort* Wt, int R, int K, int O, int G) {
    size_t tot = (size_t)R * K * O;
    wt_k<<<(int)((tot + 255) / 256), 256, 0, stream>>>(W, Wt, R, K, O, G);
  };
  wconv(W1, wt1, NREL, 128, 256, 8);   // one group of 8 -> K=1024
  wconv(r1, rt1, 1, 128, 256, 1);
  wconv(W2, wt2, NREL, 256, 256, 4);   // two groups of 4 -> K=1024
  wconv(r2, rt2, 1, 256, 256, 1);
  wconv(W3, wt3, NREL, 256, 128, 4);
  wconv(r3, rt3, 1, 256, 128, 1);

  const int gblocks = (N * 64 + 255) / 256;

  // ---- one layer: pass0 = rel-group0 + root + bias (writes C); later passes RMW; relu last ----
  auto layer = [&](const ushort* xin, int D, int NP, const ushort* Wt, const ushort* Rt,
                   const float* bias, void* Y, int O, bool relu, bool cf32) {
    dim3 g((N + 127) / 128, O / 128);
    int NR = NREL / NP;  // 8 (D=128) or 4 (D=256)
    for (int pass = 0; pass < NP; ++pass) {
      if (D == 128)
        gatherN_k<128, 8><<<gblocks, 256, 0, stream>>>(xin, slist, off, pass * 8, agg, N);
      else
        gatherN_k<256, 4><<<gblocks, 256, 0, stream>>>(xin, slist, off, pass * 4, agg, N);
      const ushort* Bt = Wt + (size_t)pass * O * (NR * D);
      const ushort* A2 = (pass == 0) ? xin : nullptr;
      const ushort* B2 = (pass == 0) ? Rt : nullptr;
      const float* bs  = (pass == 0) ? bias : nullptr;
      int rl = (relu && pass == NP - 1) ? 1 : 0;
      if (cf32)
        mgemm_k<true><<<g, 256, 0, stream>>>(agg, NR * D, Bt, A2, D, B2, bs, Y,
                                             /*loadC=*/pass > 0, rl, N, O);
      else
        mgemm_k<false><<<g, 256, 0, stream>>>(agg, NR * D, Bt, A2, D, B2, bs, Y,
                                              /*loadC=*/pass > 0, rl, N, O);
    }
  };

  layer(xb, 128, 1, wt1, rt1, b1, h1, 256, true,  false);
  layer(h1, 256, 2, wt2, rt2, b2, h2, 256, true,  false);
  layer(h2, 256, 2, wt3, rt3, b3, out, 128, false, true);
}